// Round 2
// baseline (168.214 us; speedup 1.0000x reference)
//
#include <hip/hip_runtime.h>
#include <math.h>

#define UU 32
#define HH 5120
#define RR 160
#define NN 16

// ws layout (floats), ALL plain stores -- zero atomics, zero reliance on the
// 0xAA poison:
//   tmpP[16][32][160]  at 0       (16 split-K partials of x@W_delta)
//   BP  [16][32][16]   at 81920
//   CP  [16][32][16]   at 90112
// ssm_kernel folds the 16-way partial reduction into its LDS staging pass
// (tmpP is 320 KB total -> L2/L3-hot on re-read).
//
// R7: proj restructured for latency. 96 -> 176 blocks (CU coverage 37% -> 69%):
// tmp = 16 splits x 10 r-tiles(16) , 512 thr; x slice staged to LDS ONCE
// (1 exposed global latency instead of 10), Wd double-buffered via register
// prefetch (1 sync/chunk); B/C weights staged to LDS coalesced instead of
// per-iteration strided scalar L2 reads. ssm identical to R6 (isolate the
// variable).
//
// NOTE (R4/R5 failure, prior session): fusing proj+ssm with a spin barrier
// regressed 115 -> 160 us. Two serial dispatches are the right structure.

#define TMP_WS 0
#define BP_WS  81920
#define CP_WS  90112

// bf16 helpers: unpack is a shift (no v_cvt needed); pack uses RNE.
__device__ __forceinline__ unsigned short f2bf(float f) {
    unsigned int u = __float_as_uint(f);
    u += 0x7fffu + ((u >> 16) & 1u);       // round-to-nearest-even
    return (unsigned short)(u >> 16);
}
__device__ __forceinline__ float blo(unsigned int v) { return __uint_as_float(v << 16); }
__device__ __forceinline__ float bhi(unsigned int v) { return __uint_as_float(v & 0xffff0000u); }

// shared LDS pool: tmp branch needs 32*324 + 2*512 = 11392 floats (45.5 KB);
// B/C branch needs 2*320*16 = 10240 floats (40 KB). One block/CU either way.
#define XS_STRIDE 324   // 320 + 4 pad; *4B = 1296 B, 16B-aligned rows

__global__ __launch_bounds__(512) void proj_kernel(
    const float* __restrict__ x, const float* __restrict__ Wd,
    const float* __restrict__ WB, const float* __restrict__ WC,
    float* __restrict__ ws)
{
    __shared__ float smem[32 * XS_STRIDE + 2 * 512];

    const int b = blockIdx.x;
    const int t = threadIdx.x;

    if (b < 160) {
        // ---- tmpP[s][.., r-tile rt] = x[:, s*320:(s+1)*320] @ Wd-tile.
        // 16 K-splits x 10 r-tiles of 16. Thread (u,r): one output, K=320.
        float* xs = smem;                       // [u][k] 32 x 324
        float (*wt)[512] = (float(*)[512])(smem + 32 * XS_STRIDE); // dbuf [2][32k x 16r]
        const int s  = b & 15;
        const int rt = b >> 4;
        const int r0 = rt * 16;
        const int kbase = s * 320;
        const int r = t & 15;
        const int u = t >> 4;                   // [0,32)

        // stage x slice once: 2560 float4 / 512 thr = 5 each, coalesced
        #pragma unroll
        for (int i = 0; i < 5; i++) {
            int idx4 = t + i * 512;
            int uu = idx4 / 80, k4 = idx4 % 80;
            *(float4*)&xs[uu * XS_STRIDE + k4 * 4] =
                *(const float4*)(x + uu * HH + kbase + k4 * 4);
        }
        // prefetch Wd chunk 0 into registers (128 f4, threads t<128)
        float4 wreg;
        if (t < 128) {
            int kk = t >> 2, c4 = t & 3;
            wreg = *(const float4*)(Wd + (size_t)(kbase + kk) * RR + r0 + c4 * 4);
        }

        float acc = 0.f;
        int p = 0;
        for (int c = 0; c < 10; c++, p ^= 1) {
            if (t < 128)
                *(float4*)&wt[p][(t >> 2) * 16 + (t & 3) * 4] = wreg;
            __syncthreads();
            if (t < 128 && c < 9) {
                int kk = t >> 2, c4 = t & 3;
                wreg = *(const float4*)(Wd + (size_t)(kbase + (c + 1) * 32 + kk) * RR + r0 + c4 * 4);
            }
            // compute: xs reads are 4 broadcasts/wave (b128-merged), wt reads
            // are 16-consecutive-word broadcasts -- conflict-free.
            const float* xp = &xs[u * XS_STRIDE + c * 32];
            const float* wp = &wt[p][r];
            #pragma unroll
            for (int kk = 0; kk < 32; kk++)
                acc += xp[kk] * wp[kk * 16];
        }
        ws[TMP_WS + s * 5120 + u * 160 + r0 + r] = acc;
    } else {
        // ---- BP[sb] = x-chunk @ W_B, CP[sb] = x-chunk @ W_C; 16 K-splits.
        // WB/WC tiles staged to LDS coalesced; inner loop = LDS broadcasts.
        float* wbl = smem;                      // [320][16]
        float* wcl = smem + 320 * 16;
        const int sb = b - 160;
        const int k0 = sb * 320;
        const int n  = t & 15;
        const int uu = t >> 4;                  // [0,32)

        #pragma unroll
        for (int i = 0; i < 3; i++) {
            int idx4 = t + i * 512;
            if (idx4 < 1280) {
                ((float4*)wbl)[idx4] = ((const float4*)(WB + (size_t)k0 * NN))[idx4];
                ((float4*)wcl)[idx4] = ((const float4*)(WC + (size_t)k0 * NN))[idx4];
            }
        }
        __syncthreads();

        const float* xp = x + uu * HH + k0;
        float aB = 0.f, aC = 0.f;
        #pragma unroll 4
        for (int k4 = 0; k4 < 80; k4++) {
            float4 v = *(const float4*)(xp + k4 * 4);
            const float* wb = &wbl[k4 * 64 + n];
            const float* wc = &wcl[k4 * 64 + n];
            aB += v.x * wb[0] + v.y * wb[16] + v.z * wb[32] + v.w * wb[48];
            aC += v.x * wc[0] + v.y * wc[16] + v.z * wc[32] + v.w * wc[48];
        }
        ws[BP_WS + sb * 512 + t] = aB;          // t == uu*16+n
        ws[CP_WS + sb * 512 + t] = aC;
    }
}

__device__ __forceinline__ float softplusf(float v) {
    return (v > 20.f) ? v : log1pf(expf(v));
}

// One block = 16 h-columns x 32 users, 512 threads; thread (u,q) handles ONE
// h = h0+q. tmp & W_dt staged as bf16 in LDS (stride 168 bf16 = 84 words:
// 16B-aligned, conflict-free-ish b128). The 16 tmpP/BP/CP partials are
// summed during staging (L2-hot). h-state prefetched to registers first so
// the HBM read overlaps all staging + dt compute. (Identical to R6.)
__global__ __launch_bounds__(512) void ssm_kernel(
    const float* __restrict__ x, const float* __restrict__ Wdt,
    const float* __restrict__ bdt, const float* __restrict__ Alog,
    const float* __restrict__ Dv, const float* __restrict__ hstate,
    const float* __restrict__ ws, float* __restrict__ y)
{
    __shared__ unsigned short tmp_b[32 * 168]; // [u][r] bf16
    __shared__ unsigned short wsl_b[16 * 168]; // [hh][r] bf16
    __shared__ float Bl[32 * 20];              // [u][n] pad 20
    __shared__ float Cl[32 * 20];
    __shared__ float an_l[16 * 20];            // [hh][n] = -exp(A_log)
    __shared__ float xl[32 * 17];              // [u][hh] pad 17
    __shared__ float bdtl[16];
    __shared__ float Dl[16];

    const int t  = threadIdx.x;
    const int h0 = blockIdx.x * 16;
    const int u  = t >> 4;                 // [0,32)
    const int q  = t & 15;                 // [0,16)

    // ---- prefetch h-state row (64B/thread, overlaps everything below)
    const float* hb = hstate + (size_t)(u * HH + h0 + q) * 16;
    float4 hv[4];
    #pragma unroll
    for (int k = 0; k < 4; k++) hv[k] = ((const float4*)hb)[k];

    // ---- stage tmp: sum 16 fp32 partials (L2-hot) -> bf16 LDS
    #pragma unroll
    for (int i = 0; i < 3; i++) {
        int idx4 = t + i * 512;
        if (idx4 < 1280) {
            float sx = 0.f, sy = 0.f, sz = 0.f, sw = 0.f;
            #pragma unroll
            for (int s = 0; s < 16; s++) {
                float4 v = ((const float4*)(ws + TMP_WS + s * 5120))[idx4];
                sx += v.x; sy += v.y; sz += v.z; sw += v.w;
            }
            int uu = idx4 / 40, r4 = idx4 % 40;
            unsigned int p0 = (unsigned int)f2bf(sx) | ((unsigned int)f2bf(sy) << 16);
            unsigned int p1 = (unsigned int)f2bf(sz) | ((unsigned int)f2bf(sw) << 16);
            *(uint2*)&tmp_b[uu * 168 + r4 * 4] = make_uint2(p0, p1);
        }
    }
    // ---- stage W_dt slice -> bf16 [hh][r] (64B coalesced rows)
    #pragma unroll
    for (int i = 0; i < 5; i++) {
        int idx = t + i * 512;
        int r = idx >> 4, hh = idx & 15;
        wsl_b[hh * 168 + r] = f2bf(Wdt[r * HH + h0 + hh]);
    }
    // ---- stage B, C (sum 16 partials), x slice
    {
        int uu = t >> 4, n = t & 15;
        float sb = 0.f, sc = 0.f;
        #pragma unroll
        for (int s = 0; s < 16; s++) {
            sb += ws[BP_WS + s * 512 + t];
            sc += ws[CP_WS + s * 512 + t];
        }
        Bl[uu * 20 + n] = sb;
        Cl[uu * 20 + n] = sc;
        xl[uu * 17 + n] = x[uu * HH + h0 + n];
    }
    // ---- stage -exp(A_log), bias, D
    if (t < 256) {
        int hh = t >> 4, n = t & 15;
        an_l[hh * 20 + n] = -expf(Alog[(h0 + hh) * 16 + n]);
    }
    if (t < 16) { bdtl[t] = bdt[h0 + t]; Dl[t] = Dv[h0 + t]; }
    __syncthreads();

    // ---- dt dot for h0+q (bf16 b128 reads, fp32 accumulate)
    const uint4* ta = (const uint4*)&tmp_b[u * 168];
    const uint4* wp = (const uint4*)&wsl_b[q * 168];
    float ae = 0.f, ao = 0.f;
    #pragma unroll
    for (int c = 0; c < 20; c++) {
        uint4 av = ta[c];
        uint4 wv = wp[c];
        #define MAC(X) \
            ae += blo(av.X) * blo(wv.X); ao += bhi(av.X) * bhi(wv.X);
        MAC(x) MAC(y) MAC(z) MAC(w)
        #undef MAC
    }
    const float dt = softplusf(bdtl[q] + (ae + ao));

    // ---- SSM update + output reduction
    const float xv = xl[u * 17 + q];
    const float K  = dt * xv;
    float yv = xv * Dl[q];
    #pragma unroll
    for (int qq = 0; qq < 4; qq++) {
        float4 h4 = hv[qq];
        float4 b4 = *(const float4*)&Bl[u * 20 + qq * 4];
        float4 c4 = *(const float4*)&Cl[u * 20 + qq * 4];
        float4 a4 = *(const float4*)&an_l[q * 20 + qq * 4];
        yv += (expf(dt * a4.x) * h4.x + K * b4.x) * c4.x;
        yv += (expf(dt * a4.y) * h4.y + K * b4.y) * c4.y;
        yv += (expf(dt * a4.z) * h4.z + K * b4.z) * c4.z;
        yv += (expf(dt * a4.w) * h4.w + K * b4.w) * c4.w;
    }
    y[u * HH + h0 + q] = yv;
}

extern "C" void kernel_launch(void* const* d_in, const int* in_sizes, int n_in,
                              void* d_out, int out_size, void* d_ws, size_t ws_size,
                              hipStream_t stream) {
    const float* x    = (const float*)d_in[0];
    const float* Wd   = (const float*)d_in[1];
    const float* Wdt  = (const float*)d_in[2];
    const float* bdt  = (const float*)d_in[3];
    const float* WB   = (const float*)d_in[4];
    const float* WC   = (const float*)d_in[5];
    const float* Alog = (const float*)d_in[6];
    const float* Dv   = (const float*)d_in[7];
    const float* hst  = (const float*)d_in[8];
    float* y  = (float*)d_out;
    float* ws = (float*)d_ws;

    proj_kernel<<<176, 512, 0, stream>>>(x, Wd, WB, WC, ws);
    ssm_kernel<<<320, 512, 0, stream>>>(x, Wdt, bdt, Alog, Dv, hst, ws, y);
}

// Round 3
// 107.404 us; speedup vs baseline: 1.5662x; 1.5662x over previous
//
#include <hip/hip_runtime.h>
#include <math.h>

#define UU 32
#define HH 5120
#define RR 160
#define NN 16

// ws layout (floats), ALL plain stores -- zero atomics, zero reliance on the
// 0xAA poison:
//   tmpP[16][32][160]  at 0       (16 split-K partials of x@W_delta)
//   BP  [16][32][16]   at 81920
//   CP  [16][32][16]   at 90112
//   tmpR[32][160]      at 98304   (reduced, fp32)
//   BR  [32][16]       at 103424
//   CR  [32][16]       at 103936
//
// R8 structure: proj (REVERTED verbatim to the R1-measured version: 96 blocks
// x 256 thr, atomic-free split-K partials) -> reduce (6 blocks: folds the 16
// partials ONCE, in the identical s=0..15 lanewise order ssm previously used,
// so dt inputs are bitwise unchanged) -> ssm (stages from the reduced arrays:
// 24 KB/block instead of 372 KB; chip-wide L2/L3 traffic 122 MB -> 8 MB).
//
// R2 lesson: the 512-thr whole-x-staged proj rewrite regressed proj to 72 us
// (VALUBusy 1.4%, 55 MB fetch / 103 MB write attribution). Do not revisit
// that structure. R4/R5 lesson (prior session): spin-barrier fusion regresses;
// separate dispatches are right on MI355X.

#define TMP_WS  0
#define BP_WS   81920
#define CP_WS   90112
#define TMPR_WS 98304
#define BR_WS   103424
#define CR_WS   103936

// bf16 helpers: unpack is a shift (no v_cvt needed); pack uses RNE.
__device__ __forceinline__ unsigned short f2bf(float f) {
    unsigned int u = __float_as_uint(f);
    u += 0x7fffu + ((u >> 16) & 1u);       // round-to-nearest-even
    return (unsigned short)(u >> 16);
}
__device__ __forceinline__ float blo(unsigned int v) { return __uint_as_float(v << 16); }
__device__ __forceinline__ float bhi(unsigned int v) { return __uint_as_float(v & 0xffff0000u); }

__global__ __launch_bounds__(256) void proj_kernel(
    const float* __restrict__ x, const float* __restrict__ Wd,
    const float* __restrict__ WB, const float* __restrict__ WC,
    float* __restrict__ ws)
{
    __shared__ float xs[32 * 36];    // [kk][u], row padded to 36 (16B-aligned f4 reads)
    __shared__ float wt[32 * 32];    // [kk][r-tile]

    const int b = blockIdx.x;
    const int t = threadIdx.x;

    if (b < 80) {
        // ---- tmpP[s] = x[:, s*320:(s+1)*320] @ Wd-tile, NO atomics.
        // 16 K-splits x 5 r-tiles of 32. Per thread: 4 users x 1 r-col.
        const int s  = b & 15;
        const int rt = b >> 4;
        const int r0 = rt * 32;
        const int u0 = (t >> 5) * 4;     // 8 u-groups of 4
        const int r  = t & 31;
        float acc[4] = {0.f, 0.f, 0.f, 0.f};

        for (int c = 0; c < 10; c++) {   // 10 sub-chunks of 32 k
            const int k0 = s * 320 + c * 32;
            if (c) __syncthreads();      // protect LDS re-stage
            #pragma unroll
            for (int i = 0; i < 4; i++) {
                int idx = t + i * 256;
                int u = idx >> 5, kk = idx & 31;
                xs[kk * 36 + u] = x[u * HH + k0 + kk];
            }
            {   // Wd tile: 32k x 32r = 256 float4, one per thread
                int kk = t >> 3, c4 = t & 7;
                *(float4*)&wt[kk * 32 + c4 * 4] =
                    *(const float4*)(Wd + (size_t)(k0 + kk) * RR + r0 + c4 * 4);
            }
            __syncthreads();

            #pragma unroll
            for (int kk = 0; kk < 32; kk++) {
                float4 xv = *(const float4*)&xs[kk * 36 + u0];
                float wv = wt[kk * 32 + r];
                acc[0] += xv.x * wv; acc[1] += xv.y * wv;
                acc[2] += xv.z * wv; acc[3] += xv.w * wv;
            }
        }
        #pragma unroll
        for (int i = 0; i < 4; i++)
            ws[TMP_WS + s * 5120 + (u0 + i) * 160 + r0 + r] = acc[i];
    } else {
        // ---- BP[sb] = x-chunk @ W_B, CP[sb] = x-chunk @ W_C; 16 K-splits.
        // float4-vectorized x loads; WB/WC rows are 64B wave-broadcasts.
        const int sb = b - 80;
        const int k0 = sb * 320;
        const int n  = t & 15;
        const int uu = t >> 4;                 // [0,16); also handles u=uu+16
        const float* xa = x + uu * HH + k0;
        const float* xb = x + (uu + 16) * HH + k0;
        float aB0 = 0.f, aB1 = 0.f, aC0 = 0.f, aC1 = 0.f;
        #pragma unroll 2
        for (int k4 = 0; k4 < 80; k4++) {
            float4 va = *(const float4*)(xa + k4 * 4);
            float4 vb = *(const float4*)(xb + k4 * 4);
            const int kb = (k0 + k4 * 4) * NN + n;
            #define STEP(D, CMP) { \
                float wb = WB[kb + (D) * NN]; \
                float wc = WC[kb + (D) * NN]; \
                aB0 += va.CMP * wb; aB1 += vb.CMP * wb; \
                aC0 += va.CMP * wc; aC1 += vb.CMP * wc; }
            STEP(0, x) STEP(1, y) STEP(2, z) STEP(3, w)
            #undef STEP
        }
        ws[BP_WS + sb * 512 + uu * 16 + n]        = aB0;
        ws[BP_WS + sb * 512 + (uu + 16) * 16 + n] = aB1;
        ws[CP_WS + sb * 512 + uu * 16 + n]        = aC0;
        ws[CP_WS + sb * 512 + (uu + 16) * 16 + n] = aC1;
    }
}

// Fold the 16 split-K partials once. Lanewise float4 sum in s=0..15 order ==
// exactly the order ssm's staging used before -> bitwise-identical results.
__global__ __launch_bounds__(256) void reduce_kernel(float* __restrict__ ws)
{
    const int b = blockIdx.x;
    const int t = threadIdx.x;
    if (b < 5) {
        // tmp: 1280 float4 outputs, one per thread across 5 blocks
        const int idx4 = b * 256 + t;
        float sx = 0.f, sy = 0.f, sz = 0.f, sw = 0.f;
        #pragma unroll
        for (int s = 0; s < 16; s++) {
            float4 v = ((const float4*)(ws + TMP_WS + s * 5120))[idx4];
            sx += v.x; sy += v.y; sz += v.z; sw += v.w;
        }
        float4 o; o.x = sx; o.y = sy; o.z = sz; o.w = sw;
        ((float4*)(ws + TMPR_WS))[idx4] = o;
    } else {
        // B: 128 float4 (t<128), C: 128 float4 (t>=128)
        const int base_in  = (t < 128) ? BP_WS : CP_WS;
        const int base_out = (t < 128) ? BR_WS : CR_WS;
        const int idx4 = t & 127;
        float sx = 0.f, sy = 0.f, sz = 0.f, sw = 0.f;
        #pragma unroll
        for (int s = 0; s < 16; s++) {
            float4 v = ((const float4*)(ws + base_in + s * 512))[idx4];
            sx += v.x; sy += v.y; sz += v.z; sw += v.w;
        }
        float4 o; o.x = sx; o.y = sy; o.z = sz; o.w = sw;
        ((float4*)(ws + base_out))[idx4] = o;
    }
}

__device__ __forceinline__ float softplusf(float v) {
    return (v > 20.f) ? v : log1pf(expf(v));
}

// One block = 16 h-columns x 32 users, 512 threads; thread (u,q) handles ONE
// h = h0+q. tmp & W_dt staged as bf16 in LDS (stride 168 bf16 = 84 words:
// 16B-aligned, conflict-free-ish b128). Stages from the REDUCED arrays
// (24 KB/block). h-state prefetched to registers first so the HBM read
// overlaps all staging + dt compute.
__global__ __launch_bounds__(512) void ssm_kernel(
    const float* __restrict__ x, const float* __restrict__ Wdt,
    const float* __restrict__ bdt, const float* __restrict__ Alog,
    const float* __restrict__ Dv, const float* __restrict__ hstate,
    const float* __restrict__ ws, float* __restrict__ y)
{
    __shared__ unsigned short tmp_b[32 * 168]; // [u][r] bf16
    __shared__ unsigned short wsl_b[16 * 168]; // [hh][r] bf16
    __shared__ float Bl[32 * 20];              // [u][n] pad 20
    __shared__ float Cl[32 * 20];
    __shared__ float an_l[16 * 20];            // [hh][n] = -exp(A_log)
    __shared__ float xl[32 * 17];              // [u][hh] pad 17
    __shared__ float bdtl[16];
    __shared__ float Dl[16];

    const int t  = threadIdx.x;
    const int h0 = blockIdx.x * 16;
    const int u  = t >> 4;                 // [0,32)
    const int q  = t & 15;                 // [0,16)

    // ---- prefetch h-state row (64B/thread, overlaps everything below)
    const float* hb = hstate + (size_t)(u * HH + h0 + q) * 16;
    float4 hv[4];
    #pragma unroll
    for (int k = 0; k < 4; k++) hv[k] = ((const float4*)hb)[k];

    // ---- stage tmp: reduced fp32 -> bf16 LDS (1280 f4 / 512 thr)
    #pragma unroll
    for (int i = 0; i < 3; i++) {
        int idx4 = t + i * 512;
        if (idx4 < 1280) {
            float4 v = ((const float4*)(ws + TMPR_WS))[idx4];
            int uu = idx4 / 40, r4 = idx4 % 40;
            unsigned int p0 = (unsigned int)f2bf(v.x) | ((unsigned int)f2bf(v.y) << 16);
            unsigned int p1 = (unsigned int)f2bf(v.z) | ((unsigned int)f2bf(v.w) << 16);
            *(uint2*)&tmp_b[uu * 168 + r4 * 4] = make_uint2(p0, p1);
        }
    }
    // ---- stage W_dt slice -> bf16 [hh][r] (64B coalesced rows)
    #pragma unroll
    for (int i = 0; i < 5; i++) {
        int idx = t + i * 512;
        int r = idx >> 4, hh = idx & 15;
        wsl_b[hh * 168 + r] = f2bf(Wdt[r * HH + h0 + hh]);
    }
    // ---- stage B, C (reduced), x slice
    {
        int uu = t >> 4, n = t & 15;
        Bl[uu * 20 + n] = ws[BR_WS + t];
        Cl[uu * 20 + n] = ws[CR_WS + t];
        xl[uu * 17 + n] = x[uu * HH + h0 + n];
    }
    // ---- stage -exp(A_log), bias, D
    if (t < 256) {
        int hh = t >> 4, n = t & 15;
        an_l[hh * 20 + n] = -expf(Alog[(h0 + hh) * 16 + n]);
    }
    if (t < 16) { bdtl[t] = bdt[h0 + t]; Dl[t] = Dv[h0 + t]; }
    __syncthreads();

    // ---- dt dot for h0+q (bf16 b128 reads, fp32 accumulate)
    const uint4* ta = (const uint4*)&tmp_b[u * 168];
    const uint4* wp = (const uint4*)&wsl_b[q * 168];
    float ae = 0.f, ao = 0.f;
    #pragma unroll
    for (int c = 0; c < 20; c++) {
        uint4 av = ta[c];
        uint4 wv = wp[c];
        #define MAC(X) \
            ae += blo(av.X) * blo(wv.X); ao += bhi(av.X) * bhi(wv.X);
        MAC(x) MAC(y) MAC(z) MAC(w)
        #undef MAC
    }
    const float dt = softplusf(bdtl[q] + (ae + ao));

    // ---- SSM update + output reduction
    const float xv = xl[u * 17 + q];
    const float K  = dt * xv;
    float yv = xv * Dl[q];
    #pragma unroll
    for (int qq = 0; qq < 4; qq++) {
        float4 h4 = hv[qq];
        float4 b4 = *(const float4*)&Bl[u * 20 + qq * 4];
        float4 c4 = *(const float4*)&Cl[u * 20 + qq * 4];
        float4 a4 = *(const float4*)&an_l[q * 20 + qq * 4];
        yv += (expf(dt * a4.x) * h4.x + K * b4.x) * c4.x;
        yv += (expf(dt * a4.y) * h4.y + K * b4.y) * c4.y;
        yv += (expf(dt * a4.z) * h4.z + K * b4.z) * c4.z;
        yv += (expf(dt * a4.w) * h4.w + K * b4.w) * c4.w;
    }
    y[u * HH + h0 + q] = yv;
}

extern "C" void kernel_launch(void* const* d_in, const int* in_sizes, int n_in,
                              void* d_out, int out_size, void* d_ws, size_t ws_size,
                              hipStream_t stream) {
    const float* x    = (const float*)d_in[0];
    const float* Wd   = (const float*)d_in[1];
    const float* Wdt  = (const float*)d_in[2];
    const float* bdt  = (const float*)d_in[3];
    const float* WB   = (const float*)d_in[4];
    const float* WC   = (const float*)d_in[5];
    const float* Alog = (const float*)d_in[6];
    const float* Dv   = (const float*)d_in[7];
    const float* hst  = (const float*)d_in[8];
    float* y  = (float*)d_out;
    float* ws = (float*)d_ws;

    proj_kernel<<<96, 256, 0, stream>>>(x, Wd, WB, WC, ws);
    reduce_kernel<<<6, 256, 0, stream>>>(ws);
    ssm_kernel<<<320, 512, 0, stream>>>(x, Wdt, bdt, Alog, Dv, hst, ws, y);
}

// Round 4
// 98.506 us; speedup vs baseline: 1.7077x; 1.0903x over previous
//
#include <hip/hip_runtime.h>
#include <math.h>

#define UU 32
#define HH 5120
#define RR 160
#define NN 16

// ws layout (floats), ALL plain stores -- zero atomics:
//   tmpP[32][32][160]  at 0       (32 split-K partials of x@W_delta)
//   BP  [32][32][16]   at 163840
//   CP  [32][32][16]   at 180224
//   tmpR[32][160]      at 196608  (reduced, fp32)
//   BR  [32][16]       at 201728
//   CR  [32][16]       at 202240
//
// R9: proj made SINGLE-PHASE. R1/R3's proj (~12 us, inferred from the R2
// ablation: proj_R2=73 visible, dur delta 61 -> proj_R1~12) ran 10 serial
// {stage->sync->compute->sync} chunks per block = ~10 exposed HBM latencies,
// on only 96/256 CUs. Now: 32 K-splits (K=160/block), each block stages its
// whole x-slice (23 KB) + Wd-tile (20 KB) to LDS in one burst of independent
// loads, ONE sync, then an uninterrupted 160-deep dot. 192 blocks.
// B/C blocks stage WB/WC tiles to LDS coalesced (was 640 serial scalar loads
// per thread). reduce folds 32 partials (identical-class fp32 order).
// ssm unchanged from R3 except ws-layout constants.
//
// R2 lesson: 512-thr proj with divergent register prefetch + runtime-indexed
// dbuf regressed to 72 us (VALUBusy 1.4%, 103 MB write attribution). This
// version has NO divergence in staging, NO dbuf, static indexing, 256 thr.
// R4/R5 lesson (prior session): spin-barrier fusion regresses; separate
// dispatches are right on MI355X.

#define TMP_WS  0
#define BP_WS   163840
#define CP_WS   180224
#define TMPR_WS 196608
#define BR_WS   201728
#define CR_WS   202240

#define XS_STRIDE 36   // [kk][u] rows padded: 36 words; u0 multiple of 4 -> 16B-aligned f4 reads

// bf16 helpers: unpack is a shift (no v_cvt needed); pack uses RNE.
__device__ __forceinline__ unsigned short f2bf(float f) {
    unsigned int u = __float_as_uint(f);
    u += 0x7fffu + ((u >> 16) & 1u);       // round-to-nearest-even
    return (unsigned short)(u >> 16);
}
__device__ __forceinline__ float blo(unsigned int v) { return __uint_as_float(v << 16); }
__device__ __forceinline__ float bhi(unsigned int v) { return __uint_as_float(v & 0xffff0000u); }

__global__ __launch_bounds__(256) void proj_kernel(
    const float* __restrict__ x, const float* __restrict__ Wd,
    const float* __restrict__ WB, const float* __restrict__ WC,
    float* __restrict__ ws)
{
    // tmp branch: xs 160*36=5760 + wt 160*32=5120 = 10880 floats (43.5 KB)
    // B/C branch: wbl 2560 + wcl 2560 = 5120 floats (20 KB)
    __shared__ float smem[160 * XS_STRIDE + 160 * 32];

    const int b = blockIdx.x;
    const int t = threadIdx.x;

    if (b < 160) {
        // ---- tmpP[s][:, rt*32:+32] = x[:, s*160:+160] @ Wd-tile.
        // 32 K-splits x 5 r-tiles of 32. Per thread: 4 users x 1 r-col, K=160.
        float* xs = smem;                   // [kk][u] 160 x 36
        float* wt = smem + 160 * XS_STRIDE; // [kk][r] 160 x 32
        const int s  = b & 31;
        const int rt = b >> 5;
        const int r0 = rt * 32;
        const int kbase = s * 160;
        const int u0 = (t >> 5) * 4;        // 8 u-groups of 4
        const int r  = t & 31;

        // stage x slice: 5120 elems, 20 scalar loads/thread, all independent
        // (coalesced 640B rows; LDS scatter-write ~8-way on stride-36, minor)
        #pragma unroll
        for (int i = 0; i < 20; i++) {
            int idx = t + i * 256;
            int u = idx / 160, kk = idx % 160;
            xs[kk * XS_STRIDE + u] = x[u * HH + kbase + kk];
        }
        // stage Wd tile: 160k x 32r = 1280 float4, 5/thread, independent
        #pragma unroll
        for (int i = 0; i < 5; i++) {
            int idx4 = t + i * 256;
            int kk = idx4 >> 3, r4 = idx4 & 7;
            *(float4*)&wt[kk * 32 + r4 * 4] =
                *(const float4*)(Wd + (size_t)(kbase + kk) * RR + r0 + r4 * 4);
        }
        __syncthreads();

        // uninterrupted 160-deep dot: xs f4 broadcast + wt 32-consecutive
        float acc[4] = {0.f, 0.f, 0.f, 0.f};
        #pragma unroll 8
        for (int kk = 0; kk < 160; kk++) {
            float4 xv = *(const float4*)&xs[kk * XS_STRIDE + u0];
            float wv = wt[kk * 32 + r];
            acc[0] += xv.x * wv; acc[1] += xv.y * wv;
            acc[2] += xv.z * wv; acc[3] += xv.w * wv;
        }
        #pragma unroll
        for (int i = 0; i < 4; i++)
            ws[TMP_WS + s * 5120 + (u0 + i) * 160 + r0 + r] = acc[i];
    } else {
        // ---- BP[sb] = x-chunk @ W_B, CP[sb] = x-chunk @ W_C; 32 K-splits.
        // W tiles staged to LDS coalesced once; inner loop = LDS broadcasts.
        float* wbl = smem;                  // [160][16]
        float* wcl = smem + 160 * 16;
        const int sb = b - 160;
        const int k0 = sb * 160;
        const int n  = t & 15;
        const int uu = t >> 4;              // [0,16); also handles u=uu+16

        #pragma unroll
        for (int i = 0; i < 3; i++) {
            int idx4 = t + i * 256;
            if (idx4 < 640) {
                ((float4*)wbl)[idx4] = ((const float4*)(WB + (size_t)k0 * NN))[idx4];
                ((float4*)wcl)[idx4] = ((const float4*)(WC + (size_t)k0 * NN))[idx4];
            }
        }
        __syncthreads();

        const float* xa = x + uu * HH + k0;
        const float* xb = x + (uu + 16) * HH + k0;
        float aB0 = 0.f, aB1 = 0.f, aC0 = 0.f, aC1 = 0.f;
        #pragma unroll 4
        for (int k4 = 0; k4 < 40; k4++) {
            float4 va = *(const float4*)(xa + k4 * 4);
            float4 vb = *(const float4*)(xb + k4 * 4);
            const float* wb = &wbl[k4 * 64 + n];
            const float* wc = &wcl[k4 * 64 + n];
            aB0 += va.x * wb[0] + va.y * wb[16] + va.z * wb[32] + va.w * wb[48];
            aB1 += vb.x * wb[0] + vb.y * wb[16] + vb.z * wb[32] + vb.w * wb[48];
            aC0 += va.x * wc[0] + va.y * wc[16] + va.z * wc[32] + va.w * wc[48];
            aC1 += vb.x * wc[0] + vb.y * wc[16] + vb.z * wc[32] + vb.w * wc[48];
        }
        ws[BP_WS + sb * 512 + uu * 16 + n]        = aB0;
        ws[BP_WS + sb * 512 + (uu + 16) * 16 + n] = aB1;
        ws[CP_WS + sb * 512 + uu * 16 + n]        = aC0;
        ws[CP_WS + sb * 512 + (uu + 16) * 16 + n] = aC1;
    }
}

// Fold the 32 split-K partials once. Lanewise float4 sum in s-order.
__global__ __launch_bounds__(256) void reduce_kernel(float* __restrict__ ws)
{
    const int b = blockIdx.x;
    const int t = threadIdx.x;
    if (b < 5) {
        // tmp: 1280 float4 outputs, one per thread across 5 blocks
        const int idx4 = b * 256 + t;
        float sx = 0.f, sy = 0.f, sz = 0.f, sw = 0.f;
        #pragma unroll
        for (int s = 0; s < 32; s++) {
            float4 v = ((const float4*)(ws + TMP_WS + s * 5120))[idx4];
            sx += v.x; sy += v.y; sz += v.z; sw += v.w;
        }
        float4 o; o.x = sx; o.y = sy; o.z = sz; o.w = sw;
        ((float4*)(ws + TMPR_WS))[idx4] = o;
    } else {
        // B: 128 float4 (t<128), C: 128 float4 (t>=128)
        const int base_in  = (t < 128) ? BP_WS : CP_WS;
        const int base_out = (t < 128) ? BR_WS : CR_WS;
        const int idx4 = t & 127;
        float sx = 0.f, sy = 0.f, sz = 0.f, sw = 0.f;
        #pragma unroll
        for (int s = 0; s < 32; s++) {
            float4 v = ((const float4*)(ws + base_in + s * 512))[idx4];
            sx += v.x; sy += v.y; sz += v.z; sw += v.w;
        }
        float4 o; o.x = sx; o.y = sy; o.z = sz; o.w = sw;
        ((float4*)(ws + base_out))[idx4] = o;
    }
}

__device__ __forceinline__ float softplusf(float v) {
    return (v > 20.f) ? v : log1pf(expf(v));
}

// One block = 16 h-columns x 32 users, 512 threads; thread (u,q) handles ONE
// h = h0+q. tmp & W_dt staged as bf16 in LDS (stride 168 bf16 = 84 words:
// 16B-aligned, conflict-free-ish b128). Stages from the REDUCED arrays
// (24 KB/block). h-state prefetched to registers first so the HBM read
// overlaps all staging + dt compute. (Identical to R3 except ws constants.)
__global__ __launch_bounds__(512) void ssm_kernel(
    const float* __restrict__ x, const float* __restrict__ Wdt,
    const float* __restrict__ bdt, const float* __restrict__ Alog,
    const float* __restrict__ Dv, const float* __restrict__ hstate,
    const float* __restrict__ ws, float* __restrict__ y)
{
    __shared__ unsigned short tmp_b[32 * 168]; // [u][r] bf16
    __shared__ unsigned short wsl_b[16 * 168]; // [hh][r] bf16
    __shared__ float Bl[32 * 20];              // [u][n] pad 20
    __shared__ float Cl[32 * 20];
    __shared__ float an_l[16 * 20];            // [hh][n] = -exp(A_log)
    __shared__ float xl[32 * 17];              // [u][hh] pad 17
    __shared__ float bdtl[16];
    __shared__ float Dl[16];

    const int t  = threadIdx.x;
    const int h0 = blockIdx.x * 16;
    const int u  = t >> 4;                 // [0,32)
    const int q  = t & 15;                 // [0,16)

    // ---- prefetch h-state row (64B/thread, overlaps everything below)
    const float* hb = hstate + (size_t)(u * HH + h0 + q) * 16;
    float4 hv[4];
    #pragma unroll
    for (int k = 0; k < 4; k++) hv[k] = ((const float4*)hb)[k];

    // ---- stage tmp: reduced fp32 -> bf16 LDS (1280 f4 / 512 thr)
    #pragma unroll
    for (int i = 0; i < 3; i++) {
        int idx4 = t + i * 512;
        if (idx4 < 1280) {
            float4 v = ((const float4*)(ws + TMPR_WS))[idx4];
            int uu = idx4 / 40, r4 = idx4 % 40;
            unsigned int p0 = (unsigned int)f2bf(v.x) | ((unsigned int)f2bf(v.y) << 16);
            unsigned int p1 = (unsigned int)f2bf(v.z) | ((unsigned int)f2bf(v.w) << 16);
            *(uint2*)&tmp_b[uu * 168 + r4 * 4] = make_uint2(p0, p1);
        }
    }
    // ---- stage W_dt slice -> bf16 [hh][r] (64B coalesced rows)
    #pragma unroll
    for (int i = 0; i < 5; i++) {
        int idx = t + i * 512;
        int r = idx >> 4, hh = idx & 15;
        wsl_b[hh * 168 + r] = f2bf(Wdt[r * HH + h0 + hh]);
    }
    // ---- stage B, C (reduced), x slice
    {
        int uu = t >> 4, n = t & 15;
        Bl[uu * 20 + n] = ws[BR_WS + t];
        Cl[uu * 20 + n] = ws[CR_WS + t];
        xl[uu * 17 + n] = x[uu * HH + h0 + n];
    }
    // ---- stage -exp(A_log), bias, D
    if (t < 256) {
        int hh = t >> 4, n = t & 15;
        an_l[hh * 20 + n] = -expf(Alog[(h0 + hh) * 16 + n]);
    }
    if (t < 16) { bdtl[t] = bdt[h0 + t]; Dl[t] = Dv[h0 + t]; }
    __syncthreads();

    // ---- dt dot for h0+q (bf16 b128 reads, fp32 accumulate)
    const uint4* ta = (const uint4*)&tmp_b[u * 168];
    const uint4* wp = (const uint4*)&wsl_b[q * 168];
    float ae = 0.f, ao = 0.f;
    #pragma unroll
    for (int c = 0; c < 20; c++) {
        uint4 av = ta[c];
        uint4 wv = wp[c];
        #define MAC(X) \
            ae += blo(av.X) * blo(wv.X); ao += bhi(av.X) * bhi(wv.X);
        MAC(x) MAC(y) MAC(z) MAC(w)
        #undef MAC
    }
    const float dt = softplusf(bdtl[q] + (ae + ao));

    // ---- SSM update + output reduction
    const float xv = xl[u * 17 + q];
    const float K  = dt * xv;
    float yv = xv * Dl[q];
    #pragma unroll
    for (int qq = 0; qq < 4; qq++) {
        float4 h4 = hv[qq];
        float4 b4 = *(const float4*)&Bl[u * 20 + qq * 4];
        float4 c4 = *(const float4*)&Cl[u * 20 + qq * 4];
        float4 a4 = *(const float4*)&an_l[q * 20 + qq * 4];
        yv += (expf(dt * a4.x) * h4.x + K * b4.x) * c4.x;
        yv += (expf(dt * a4.y) * h4.y + K * b4.y) * c4.y;
        yv += (expf(dt * a4.z) * h4.z + K * b4.z) * c4.z;
        yv += (expf(dt * a4.w) * h4.w + K * b4.w) * c4.w;
    }
    y[u * HH + h0 + q] = yv;
}

extern "C" void kernel_launch(void* const* d_in, const int* in_sizes, int n_in,
                              void* d_out, int out_size, void* d_ws, size_t ws_size,
                              hipStream_t stream) {
    const float* x    = (const float*)d_in[0];
    const float* Wd   = (const float*)d_in[1];
    const float* Wdt  = (const float*)d_in[2];
    const float* bdt  = (const float*)d_in[3];
    const float* WB   = (const float*)d_in[4];
    const float* WC   = (const float*)d_in[5];
    const float* Alog = (const float*)d_in[6];
    const float* Dv   = (const float*)d_in[7];
    const float* hst  = (const float*)d_in[8];
    float* y  = (float*)d_out;
    float* ws = (float*)d_ws;

    proj_kernel<<<192, 256, 0, stream>>>(x, Wd, WB, WC, ws);
    reduce_kernel<<<6, 256, 0, stream>>>(ws);
    ssm_kernel<<<320, 512, 0, stream>>>(x, Wdt, bdt, Alog, Dv, hst, ws, y);
}

// Round 5
// 95.539 us; speedup vs baseline: 1.7607x; 1.0311x over previous
//
#include <hip/hip_runtime.h>
#include <math.h>

#define UU 32
#define HH 5120
#define RR 160
#define NN 16

// ws layout (floats), ALL plain stores -- zero atomics:
//   tmpP[32][32][160]  at 0       (32 split-K partials of x@W_delta)
//   BP  [32][32][16]   at 163840
//   CP  [32][32][16]   at 180224
//   tmpR[32][160]      at 196608  (reduced, fp32)
//   BR  [32][16]       at 201728
//   CR  [32][16]       at 202240
//
// R10: ssm rebalanced. 320 blocks on 256 CUs made 64 CUs run 2 blocks
// (2x end time); now 256 blocks x 640 thr, 20 h-cols each (5120=256x20) --
// exactly one block/CU. Inner-loop expf -> __expf (v_mul+v_exp, ~8 fewer
// instrs x16/thread); xl LDS stage dropped (each thread only read its own
// x value -- now a direct early global load). proj+reduce unchanged from R4
// (measured: single-phase proj took total 107.4 -> 98.5).
//
// R2 lesson: no divergent register prefetch / runtime-indexed dbuf in proj.
// R4/R5 lesson (prior session): spin-barrier fusion regresses; separate
// dispatches are right on MI355X.

#define TMP_WS  0
#define BP_WS   163840
#define CP_WS   180224
#define TMPR_WS 196608
#define BR_WS   201728
#define CR_WS   202240

#define XS_STRIDE 36   // [kk][u] rows padded: 36 words; u0 multiple of 4 -> 16B-aligned f4 reads

// bf16 helpers: unpack is a shift (no v_cvt needed); pack uses RNE.
__device__ __forceinline__ unsigned short f2bf(float f) {
    unsigned int u = __float_as_uint(f);
    u += 0x7fffu + ((u >> 16) & 1u);       // round-to-nearest-even
    return (unsigned short)(u >> 16);
}
__device__ __forceinline__ float blo(unsigned int v) { return __uint_as_float(v << 16); }
__device__ __forceinline__ float bhi(unsigned int v) { return __uint_as_float(v & 0xffff0000u); }

__global__ __launch_bounds__(256) void proj_kernel(
    const float* __restrict__ x, const float* __restrict__ Wd,
    const float* __restrict__ WB, const float* __restrict__ WC,
    float* __restrict__ ws)
{
    // tmp branch: xs 160*36=5760 + wt 160*32=5120 = 10880 floats (43.5 KB)
    // B/C branch: wbl 2560 + wcl 2560 = 5120 floats (20 KB)
    __shared__ float smem[160 * XS_STRIDE + 160 * 32];

    const int b = blockIdx.x;
    const int t = threadIdx.x;

    if (b < 160) {
        // ---- tmpP[s][:, rt*32:+32] = x[:, s*160:+160] @ Wd-tile.
        // 32 K-splits x 5 r-tiles of 32. Per thread: 4 users x 1 r-col, K=160.
        float* xs = smem;                   // [kk][u] 160 x 36
        float* wt = smem + 160 * XS_STRIDE; // [kk][r] 160 x 32
        const int s  = b & 31;
        const int rt = b >> 5;
        const int r0 = rt * 32;
        const int kbase = s * 160;
        const int u0 = (t >> 5) * 4;        // 8 u-groups of 4
        const int r  = t & 31;

        // stage x slice: 5120 elems, 20 scalar loads/thread, all independent
        // (coalesced 640B rows; LDS scatter-write ~8-way on stride-36, minor)
        #pragma unroll
        for (int i = 0; i < 20; i++) {
            int idx = t + i * 256;
            int u = idx / 160, kk = idx % 160;
            xs[kk * XS_STRIDE + u] = x[u * HH + kbase + kk];
        }
        // stage Wd tile: 160k x 32r = 1280 float4, 5/thread, independent
        #pragma unroll
        for (int i = 0; i < 5; i++) {
            int idx4 = t + i * 256;
            int kk = idx4 >> 3, r4 = idx4 & 7;
            *(float4*)&wt[kk * 32 + r4 * 4] =
                *(const float4*)(Wd + (size_t)(kbase + kk) * RR + r0 + r4 * 4);
        }
        __syncthreads();

        // uninterrupted 160-deep dot: xs f4 broadcast + wt 32-consecutive
        float acc[4] = {0.f, 0.f, 0.f, 0.f};
        #pragma unroll 8
        for (int kk = 0; kk < 160; kk++) {
            float4 xv = *(const float4*)&xs[kk * XS_STRIDE + u0];
            float wv = wt[kk * 32 + r];
            acc[0] += xv.x * wv; acc[1] += xv.y * wv;
            acc[2] += xv.z * wv; acc[3] += xv.w * wv;
        }
        #pragma unroll
        for (int i = 0; i < 4; i++)
            ws[TMP_WS + s * 5120 + (u0 + i) * 160 + r0 + r] = acc[i];
    } else {
        // ---- BP[sb] = x-chunk @ W_B, CP[sb] = x-chunk @ W_C; 32 K-splits.
        // W tiles staged to LDS coalesced once; inner loop = LDS broadcasts.
        float* wbl = smem;                  // [160][16]
        float* wcl = smem + 160 * 16;
        const int sb = b - 160;
        const int k0 = sb * 160;
        const int n  = t & 15;
        const int uu = t >> 4;              // [0,16); also handles u=uu+16

        #pragma unroll
        for (int i = 0; i < 3; i++) {
            int idx4 = t + i * 256;
            if (idx4 < 640) {
                ((float4*)wbl)[idx4] = ((const float4*)(WB + (size_t)k0 * NN))[idx4];
                ((float4*)wcl)[idx4] = ((const float4*)(WC + (size_t)k0 * NN))[idx4];
            }
        }
        __syncthreads();

        const float* xa = x + uu * HH + k0;
        const float* xb = x + (uu + 16) * HH + k0;
        float aB0 = 0.f, aB1 = 0.f, aC0 = 0.f, aC1 = 0.f;
        #pragma unroll 4
        for (int k4 = 0; k4 < 40; k4++) {
            float4 va = *(const float4*)(xa + k4 * 4);
            float4 vb = *(const float4*)(xb + k4 * 4);
            const float* wb = &wbl[k4 * 64 + n];
            const float* wc = &wcl[k4 * 64 + n];
            aB0 += va.x * wb[0] + va.y * wb[16] + va.z * wb[32] + va.w * wb[48];
            aB1 += vb.x * wb[0] + vb.y * wb[16] + vb.z * wb[32] + vb.w * wb[48];
            aC0 += va.x * wc[0] + va.y * wc[16] + va.z * wc[32] + va.w * wc[48];
            aC1 += vb.x * wc[0] + vb.y * wc[16] + vb.z * wc[32] + vb.w * wc[48];
        }
        ws[BP_WS + sb * 512 + uu * 16 + n]        = aB0;
        ws[BP_WS + sb * 512 + (uu + 16) * 16 + n] = aB1;
        ws[CP_WS + sb * 512 + uu * 16 + n]        = aC0;
        ws[CP_WS + sb * 512 + (uu + 16) * 16 + n] = aC1;
    }
}

// Fold the 32 split-K partials once. Lanewise float4 sum in s-order.
__global__ __launch_bounds__(256) void reduce_kernel(float* __restrict__ ws)
{
    const int b = blockIdx.x;
    const int t = threadIdx.x;
    if (b < 5) {
        // tmp: 1280 float4 outputs, one per thread across 5 blocks
        const int idx4 = b * 256 + t;
        float sx = 0.f, sy = 0.f, sz = 0.f, sw = 0.f;
        #pragma unroll
        for (int s = 0; s < 32; s++) {
            float4 v = ((const float4*)(ws + TMP_WS + s * 5120))[idx4];
            sx += v.x; sy += v.y; sz += v.z; sw += v.w;
        }
        float4 o; o.x = sx; o.y = sy; o.z = sz; o.w = sw;
        ((float4*)(ws + TMPR_WS))[idx4] = o;
    } else {
        // B: 128 float4 (t<128), C: 128 float4 (t>=128)
        const int base_in  = (t < 128) ? BP_WS : CP_WS;
        const int base_out = (t < 128) ? BR_WS : CR_WS;
        const int idx4 = t & 127;
        float sx = 0.f, sy = 0.f, sz = 0.f, sw = 0.f;
        #pragma unroll
        for (int s = 0; s < 32; s++) {
            float4 v = ((const float4*)(ws + base_in + s * 512))[idx4];
            sx += v.x; sy += v.y; sz += v.z; sw += v.w;
        }
        float4 o; o.x = sx; o.y = sy; o.z = sz; o.w = sw;
        ((float4*)(ws + base_out))[idx4] = o;
    }
}

__device__ __forceinline__ float softplusf(float v) {
    return (v > 20.f) ? v : log1pf(expf(v));
}

// One block = 20 h-columns x 32 users, 640 threads; 256 blocks = exactly one
// per CU (5120 = 256*20). Thread (u,q) handles ONE h = h0+q. tmp & W_dt
// staged as bf16 in LDS (stride 168 bf16: 16B-aligned rows). Stages from the
// REDUCED arrays. h-state + own-x prefetched to registers first so the HBM
// read overlaps all staging + dt compute. Inner exp via __expf (v_exp_f32).
__global__ __launch_bounds__(640) void ssm_kernel(
    const float* __restrict__ x, const float* __restrict__ Wdt,
    const float* __restrict__ bdt, const float* __restrict__ Alog,
    const float* __restrict__ Dv, const float* __restrict__ hstate,
    const float* __restrict__ ws, float* __restrict__ y)
{
    __shared__ unsigned short tmp_b[32 * 168]; // [u][r] bf16
    __shared__ unsigned short wsl_b[20 * 168]; // [hh][r] bf16
    __shared__ float Bl[32 * 20];              // [u][n] pad 20
    __shared__ float Cl[32 * 20];
    __shared__ float an_l[20 * 20];            // [hh][n] = -exp(A_log), pad 20
    __shared__ float bdtl[20];
    __shared__ float Dl[20];

    const int t  = threadIdx.x;
    const int h0 = blockIdx.x * 20;
    const int u  = t / 20;                 // [0,32)
    const int q  = t % 20;                 // [0,20)

    // ---- prefetch h-state row (64B/thread) + own x value; overlaps staging
    const float* hb = hstate + (size_t)(u * HH + h0 + q) * 16;
    float4 hv[4];
    #pragma unroll
    for (int k = 0; k < 4; k++) hv[k] = ((const float4*)hb)[k];
    const float xv = x[u * HH + h0 + q];

    // ---- stage tmp: reduced fp32 -> bf16 LDS (1280 f4 = 2*640)
    #pragma unroll
    for (int i = 0; i < 2; i++) {
        int idx4 = t + i * 640;
        float4 v = ((const float4*)(ws + TMPR_WS))[idx4];
        int uu = idx4 / 40, r4 = idx4 % 40;
        unsigned int p0 = (unsigned int)f2bf(v.x) | ((unsigned int)f2bf(v.y) << 16);
        unsigned int p1 = (unsigned int)f2bf(v.z) | ((unsigned int)f2bf(v.w) << 16);
        *(uint2*)&tmp_b[uu * 168 + r4 * 4] = make_uint2(p0, p1);
    }
    // ---- stage W_dt slice -> bf16 [hh][r] (3200 = 5*640, 80B coalesced rows)
    #pragma unroll
    for (int i = 0; i < 5; i++) {
        int idx = t + i * 640;
        int r = idx / 20, hh = idx % 20;
        wsl_b[hh * 168 + r] = f2bf(Wdt[r * HH + h0 + hh]);
    }
    // ---- stage B, C (reduced)
    if (t < 512) {
        int uu = t >> 4, n = t & 15;
        Bl[uu * 20 + n] = ws[BR_WS + t];
        Cl[uu * 20 + n] = ws[CR_WS + t];
    }
    // ---- stage -exp(A_log), bias, D
    if (t < 320) {
        int hh = t >> 4, n = t & 15;
        an_l[hh * 20 + n] = -expf(Alog[(h0 + hh) * 16 + n]);
    }
    if (t < 20) { bdtl[t] = bdt[h0 + t]; Dl[t] = Dv[h0 + t]; }
    __syncthreads();

    // ---- dt dot for h0+q (bf16 b128 reads, fp32 accumulate)
    const uint4* ta = (const uint4*)&tmp_b[u * 168];
    const uint4* wp = (const uint4*)&wsl_b[q * 168];
    float ae = 0.f, ao = 0.f;
    #pragma unroll
    for (int c = 0; c < 20; c++) {
        uint4 av = ta[c];
        uint4 wv = wp[c];
        #define MAC(X) \
            ae += blo(av.X) * blo(wv.X); ao += bhi(av.X) * bhi(wv.X);
        MAC(x) MAC(y) MAC(z) MAC(w)
        #undef MAC
    }
    const float dt = softplusf(bdtl[q] + (ae + ao));

    // ---- SSM update + output reduction (__expf = v_mul+v_exp, ~2 ulp; the
    // 0.5 absmax is bf16-dt dominated, so this is invisible)
    const float K  = dt * xv;
    float yv = xv * Dl[q];
    #pragma unroll
    for (int qq = 0; qq < 4; qq++) {
        float4 h4 = hv[qq];
        float4 b4 = *(const float4*)&Bl[u * 20 + qq * 4];
        float4 c4 = *(const float4*)&Cl[u * 20 + qq * 4];
        float4 a4 = *(const float4*)&an_l[q * 20 + qq * 4];
        yv += (__expf(dt * a4.x) * h4.x + K * b4.x) * c4.x;
        yv += (__expf(dt * a4.y) * h4.y + K * b4.y) * c4.y;
        yv += (__expf(dt * a4.z) * h4.z + K * b4.z) * c4.z;
        yv += (__expf(dt * a4.w) * h4.w + K * b4.w) * c4.w;
    }
    y[u * HH + h0 + q] = yv;
}

extern "C" void kernel_launch(void* const* d_in, const int* in_sizes, int n_in,
                              void* d_out, int out_size, void* d_ws, size_t ws_size,
                              hipStream_t stream) {
    const float* x    = (const float*)d_in[0];
    const float* Wd   = (const float*)d_in[1];
    const float* Wdt  = (const float*)d_in[2];
    const float* bdt  = (const float*)d_in[3];
    const float* WB   = (const float*)d_in[4];
    const float* WC   = (const float*)d_in[5];
    const float* Alog = (const float*)d_in[6];
    const float* Dv   = (const float*)d_in[7];
    const float* hst  = (const float*)d_in[8];
    float* y  = (float*)d_out;
    float* ws = (float*)d_ws;

    proj_kernel<<<192, 256, 0, stream>>>(x, Wd, WB, WC, ws);
    reduce_kernel<<<6, 256, 0, stream>>>(ws);
    ssm_kernel<<<256, 640, 0, stream>>>(x, Wdt, bdt, Alog, Dv, hst, ws, y);
}

// Round 6
// 94.909 us; speedup vs baseline: 1.7724x; 1.0066x over previous
//
#include <hip/hip_runtime.h>
#include <math.h>

#define UU 32
#define HH 5120
#define RR 160
#define NN 16

// ws layout (floats), ALL plain stores -- zero atomics:
//   tmpP[32][32][160]  at 0       (32 split-K partials of x@W_delta)
//   BP  [32][32][16]   at 163840
//   CP  [32][32][16]   at 180224
//   tmpR[32][160]      at 196608  (reduced, fp32)
//   BR  [32][16]       at 201728
//   CR  [32][16]       at 202240
//
// R11: ssm dt-dot switched bf16 -> fp32 LDS. The bf16 path cost 20x(16 unpack
// + 16 fma) = 640 VALU + 60 ds_read per thread; fp32 is 40x(2 ds_read_b128 +
// 4 fma) = 160 fma + 80 ds_read. LDS is not a constraint (1 block/CU, 41 KB
// of 160 KB). Also more accurate dt (bf16 dt was the absmax=0.5 source --
// absmax dropping is the theory's correctness probe). Softplus via
// __logf(1+__expf). proj/reduce unchanged (measured-good).
//
// History: R10 rebalanced ssm to 256 blk x 640 thr (one per CU) + __expf
// (98.5 -> 95.5). R9 single-phase proj (107.4 -> 98.5). R8 separate reduce
// dispatch. R2 lesson: no divergent register prefetch / runtime-indexed dbuf.
// Prior-session lesson: spin-barrier fusion regresses; separate dispatches.

#define TMP_WS  0
#define BP_WS   163840
#define CP_WS   180224
#define TMPR_WS 196608
#define BR_WS   201728
#define CR_WS   202240

#define XS_STRIDE 36   // proj [kk][u] rows padded: u0 multiple of 4 -> 16B-aligned f4 reads
#define TS 164         // ssm fp32 LDS row stride (words): 16B-aligned, <=3-way read aliasing

// bf16 helpers (still used by nothing hot -- kept for reference/compat)
__device__ __forceinline__ unsigned short f2bf(float f) {
    unsigned int u = __float_as_uint(f);
    u += 0x7fffu + ((u >> 16) & 1u);       // round-to-nearest-even
    return (unsigned short)(u >> 16);
}

__global__ __launch_bounds__(256) void proj_kernel(
    const float* __restrict__ x, const float* __restrict__ Wd,
    const float* __restrict__ WB, const float* __restrict__ WC,
    float* __restrict__ ws)
{
    // tmp branch: xs 160*36=5760 + wt 160*32=5120 = 10880 floats (43.5 KB)
    // B/C branch: wbl 2560 + wcl 2560 = 5120 floats (20 KB)
    __shared__ float smem[160 * XS_STRIDE + 160 * 32];

    const int b = blockIdx.x;
    const int t = threadIdx.x;

    if (b < 160) {
        // ---- tmpP[s][:, rt*32:+32] = x[:, s*160:+160] @ Wd-tile.
        // 32 K-splits x 5 r-tiles of 32. Per thread: 4 users x 1 r-col, K=160.
        float* xs = smem;                   // [kk][u] 160 x 36
        float* wt = smem + 160 * XS_STRIDE; // [kk][r] 160 x 32
        const int s  = b & 31;
        const int rt = b >> 5;
        const int r0 = rt * 32;
        const int kbase = s * 160;
        const int u0 = (t >> 5) * 4;        // 8 u-groups of 4
        const int r  = t & 31;

        // stage x slice: 5120 elems, 20 scalar loads/thread, all independent
        // (coalesced 640B rows; LDS scatter-write ~8-way on stride-36, minor)
        #pragma unroll
        for (int i = 0; i < 20; i++) {
            int idx = t + i * 256;
            int u = idx / 160, kk = idx % 160;
            xs[kk * XS_STRIDE + u] = x[u * HH + kbase + kk];
        }
        // stage Wd tile: 160k x 32r = 1280 float4, 5/thread, independent
        #pragma unroll
        for (int i = 0; i < 5; i++) {
            int idx4 = t + i * 256;
            int kk = idx4 >> 3, r4 = idx4 & 7;
            *(float4*)&wt[kk * 32 + r4 * 4] =
                *(const float4*)(Wd + (size_t)(kbase + kk) * RR + r0 + r4 * 4);
        }
        __syncthreads();

        // uninterrupted 160-deep dot: xs f4 broadcast + wt 32-consecutive
        float acc[4] = {0.f, 0.f, 0.f, 0.f};
        #pragma unroll 8
        for (int kk = 0; kk < 160; kk++) {
            float4 xv = *(const float4*)&xs[kk * XS_STRIDE + u0];
            float wv = wt[kk * 32 + r];
            acc[0] += xv.x * wv; acc[1] += xv.y * wv;
            acc[2] += xv.z * wv; acc[3] += xv.w * wv;
        }
        #pragma unroll
        for (int i = 0; i < 4; i++)
            ws[TMP_WS + s * 5120 + (u0 + i) * 160 + r0 + r] = acc[i];
    } else {
        // ---- BP[sb] = x-chunk @ W_B, CP[sb] = x-chunk @ W_C; 32 K-splits.
        // W tiles staged to LDS coalesced once; inner loop = LDS broadcasts.
        float* wbl = smem;                  // [160][16]
        float* wcl = smem + 160 * 16;
        const int sb = b - 160;
        const int k0 = sb * 160;
        const int n  = t & 15;
        const int uu = t >> 4;              // [0,16); also handles u=uu+16

        #pragma unroll
        for (int i = 0; i < 3; i++) {
            int idx4 = t + i * 256;
            if (idx4 < 640) {
                ((float4*)wbl)[idx4] = ((const float4*)(WB + (size_t)k0 * NN))[idx4];
                ((float4*)wcl)[idx4] = ((const float4*)(WC + (size_t)k0 * NN))[idx4];
            }
        }
        __syncthreads();

        const float* xa = x + uu * HH + k0;
        const float* xb = x + (uu + 16) * HH + k0;
        float aB0 = 0.f, aB1 = 0.f, aC0 = 0.f, aC1 = 0.f;
        #pragma unroll 4
        for (int k4 = 0; k4 < 40; k4++) {
            float4 va = *(const float4*)(xa + k4 * 4);
            float4 vb = *(const float4*)(xb + k4 * 4);
            const float* wb = &wbl[k4 * 64 + n];
            const float* wc = &wcl[k4 * 64 + n];
            aB0 += va.x * wb[0] + va.y * wb[16] + va.z * wb[32] + va.w * wb[48];
            aB1 += vb.x * wb[0] + vb.y * wb[16] + vb.z * wb[32] + vb.w * wb[48];
            aC0 += va.x * wc[0] + va.y * wc[16] + va.z * wc[32] + va.w * wc[48];
            aC1 += vb.x * wc[0] + vb.y * wc[16] + vb.z * wc[32] + vb.w * wc[48];
        }
        ws[BP_WS + sb * 512 + uu * 16 + n]        = aB0;
        ws[BP_WS + sb * 512 + (uu + 16) * 16 + n] = aB1;
        ws[CP_WS + sb * 512 + uu * 16 + n]        = aC0;
        ws[CP_WS + sb * 512 + (uu + 16) * 16 + n] = aC1;
    }
}

// Fold the 32 split-K partials once. Lanewise float4 sum in s-order.
__global__ __launch_bounds__(256) void reduce_kernel(float* __restrict__ ws)
{
    const int b = blockIdx.x;
    const int t = threadIdx.x;
    if (b < 5) {
        // tmp: 1280 float4 outputs, one per thread across 5 blocks
        const int idx4 = b * 256 + t;
        float sx = 0.f, sy = 0.f, sz = 0.f, sw = 0.f;
        #pragma unroll
        for (int s = 0; s < 32; s++) {
            float4 v = ((const float4*)(ws + TMP_WS + s * 5120))[idx4];
            sx += v.x; sy += v.y; sz += v.z; sw += v.w;
        }
        float4 o; o.x = sx; o.y = sy; o.z = sz; o.w = sw;
        ((float4*)(ws + TMPR_WS))[idx4] = o;
    } else {
        // B: 128 float4 (t<128), C: 128 float4 (t>=128)
        const int base_in  = (t < 128) ? BP_WS : CP_WS;
        const int base_out = (t < 128) ? BR_WS : CR_WS;
        const int idx4 = t & 127;
        float sx = 0.f, sy = 0.f, sz = 0.f, sw = 0.f;
        #pragma unroll
        for (int s = 0; s < 32; s++) {
            float4 v = ((const float4*)(ws + base_in + s * 512))[idx4];
            sx += v.x; sy += v.y; sz += v.z; sw += v.w;
        }
        float4 o; o.x = sx; o.y = sy; o.z = sz; o.w = sw;
        ((float4*)(ws + base_out))[idx4] = o;
    }
}

__device__ __forceinline__ float softplusf(float v) {
    return (v > 20.f) ? v : __logf(1.f + __expf(v));
}

// One block = 20 h-columns x 32 users, 640 threads; 256 blocks = exactly one
// per CU (5120 = 256*20). Thread (u,q) handles ONE h = h0+q. tmp & W_dt now
// staged as FP32 in LDS (stride TS=164 words: 16B-aligned, <=3-way read
// aliasing). h-state + own-x prefetched to registers first so the HBM read
// overlaps all staging + dt compute. dt dot: 40 x {2 ds_read_b128 + 4 fma}
// with 4 independent accumulator chains.
__global__ __launch_bounds__(640) void ssm_kernel(
    const float* __restrict__ x, const float* __restrict__ Wdt,
    const float* __restrict__ bdt, const float* __restrict__ Alog,
    const float* __restrict__ Dv, const float* __restrict__ hstate,
    const float* __restrict__ ws, float* __restrict__ y)
{
    __shared__ float tmp_l[32 * TS];   // [u][r] fp32
    __shared__ float wsl  [20 * TS];   // [hh][r] fp32
    __shared__ float Bl[32 * 20];      // [u][n] pad 20
    __shared__ float Cl[32 * 20];
    __shared__ float an_l[20 * 20];    // [hh][n] = -exp(A_log), pad 20
    __shared__ float bdtl[20];
    __shared__ float Dl[20];

    const int t  = threadIdx.x;
    const int h0 = blockIdx.x * 20;
    const int u  = t / 20;                 // [0,32)
    const int q  = t % 20;                 // [0,20)

    // ---- prefetch h-state row (64B/thread) + own x value; overlaps staging
    const float* hb = hstate + (size_t)(u * HH + h0 + q) * 16;
    float4 hv[4];
    #pragma unroll
    for (int k = 0; k < 4; k++) hv[k] = ((const float4*)hb)[k];
    const float xv = x[u * HH + h0 + q];

    // ---- stage tmp: reduced fp32 -> fp32 LDS (1280 f4 = 2*640, contiguous
    // per-row writes -> conflict-free)
    #pragma unroll
    for (int i = 0; i < 2; i++) {
        int idx4 = t + i * 640;
        float4 v = ((const float4*)(ws + TMPR_WS))[idx4];
        int uu = idx4 / 40, r4 = idx4 % 40;
        *(float4*)&tmp_l[uu * TS + r4 * 4] = v;
    }
    // ---- stage W_dt slice -> fp32 [hh][r] (3200 = 5*640)
    #pragma unroll
    for (int i = 0; i < 5; i++) {
        int idx = t + i * 640;
        int r = idx / 20, hh = idx % 20;
        wsl[hh * TS + r] = Wdt[r * HH + h0 + hh];
    }
    // ---- stage B, C (reduced)
    if (t < 512) {
        int uu = t >> 4, n = t & 15;
        Bl[uu * 20 + n] = ws[BR_WS + t];
        Cl[uu * 20 + n] = ws[CR_WS + t];
    }
    // ---- stage -exp(A_log), bias, D
    if (t < 320) {
        int hh = t >> 4, n = t & 15;
        an_l[hh * 20 + n] = -__expf(Alog[(h0 + hh) * 16 + n]);
    }
    if (t < 20) { bdtl[t] = bdt[h0 + t]; Dl[t] = Dv[h0 + t]; }
    __syncthreads();

    // ---- dt dot for h0+q: fp32, 40 f4-pairs, 4 independent chains
    const float4* ta = (const float4*)&tmp_l[u * TS];
    const float4* wp = (const float4*)&wsl[q * TS];
    float ax = 0.f, ay = 0.f, az = 0.f, aw = 0.f;
    #pragma unroll 8
    for (int c = 0; c < 40; c++) {
        float4 a = ta[c];
        float4 w = wp[c];
        ax += a.x * w.x; ay += a.y * w.y;
        az += a.z * w.z; aw += a.w * w.w;
    }
    const float dt = softplusf(bdtl[q] + ((ax + ay) + (az + aw)));

    // ---- SSM update + output reduction (__expf = v_mul+v_exp)
    const float K  = dt * xv;
    float yv = xv * Dl[q];
    #pragma unroll
    for (int qq = 0; qq < 4; qq++) {
        float4 h4 = hv[qq];
        float4 b4 = *(const float4*)&Bl[u * 20 + qq * 4];
        float4 c4 = *(const float4*)&Cl[u * 20 + qq * 4];
        float4 a4 = *(const float4*)&an_l[q * 20 + qq * 4];
        yv += (__expf(dt * a4.x) * h4.x + K * b4.x) * c4.x;
        yv += (__expf(dt * a4.y) * h4.y + K * b4.y) * c4.y;
        yv += (__expf(dt * a4.z) * h4.z + K * b4.z) * c4.z;
        yv += (__expf(dt * a4.w) * h4.w + K * b4.w) * c4.w;
    }
    y[u * HH + h0 + q] = yv;
}

extern "C" void kernel_launch(void* const* d_in, const int* in_sizes, int n_in,
                              void* d_out, int out_size, void* d_ws, size_t ws_size,
                              hipStream_t stream) {
    const float* x    = (const float*)d_in[0];
    const float* Wd   = (const float*)d_in[1];
    const float* Wdt  = (const float*)d_in[2];
    const float* bdt  = (const float*)d_in[3];
    const float* WB   = (const float*)d_in[4];
    const float* WC   = (const float*)d_in[5];
    const float* Alog = (const float*)d_in[6];
    const float* Dv   = (const float*)d_in[7];
    const float* hst  = (const float*)d_in[8];
    float* y  = (float*)d_out;
    float* ws = (float*)d_ws;

    proj_kernel<<<192, 256, 0, stream>>>(x, Wd, WB, WC, ws);
    reduce_kernel<<<6, 256, 0, stream>>>(ws);
    ssm_kernel<<<256, 640, 0, stream>>>(x, Wdt, bdt, Alog, Dv, hst, ws, y);
}